// Round 1
// baseline (449.990 us; speedup 1.0000x reference)
//
#include <hip/hip_runtime.h>
#include <hip/hip_bf16.h>

typedef __attribute__((ext_vector_type(8))) short short8v;
typedef __attribute__((ext_vector_type(8))) unsigned short ushort8v;
typedef __attribute__((ext_vector_type(4))) float f32x4;

#define N_NBR 65536
#define INIT_DIM 512
#define HID 1024
#define OUT_DIM 64
#define BM 64

static __device__ __forceinline__ unsigned short f2bf(float f) {
  unsigned int u = __float_as_uint(f);
  u += 0x7fff + ((u >> 16) & 1);   // round-to-nearest-even
  return (unsigned short)(u >> 16);
}

__global__ __launch_bounds__(256) void k_zero(float* __restrict__ acc) {
  for (int j = threadIdx.x; j < HID; j += 256) acc[j] = 0.f;
}

// Convert 3x [1024][512] f32 weight matrices to bf16 (row-major, contiguous)
__global__ __launch_bounds__(256) void k_convw(const float* __restrict__ wa,
                                               const float* __restrict__ wb,
                                               const float* __restrict__ wc,
                                               unsigned short* __restrict__ out) {
  int c = blockIdx.x * 256 + threadIdx.x;   // 196608 chunks of 8 elems
  int t = c >> 16;                          // 65536 chunks per matrix
  int off = (c & 65535) * 8;
  const float* src = (t == 0) ? wa : (t == 1) ? wb : wc;
  const float4* p = (const float4*)(src + off);
  float4 a = p[0], b = p[1];
  ushort8v v;
  v[0]=f2bf(a.x); v[1]=f2bf(a.y); v[2]=f2bf(a.z); v[3]=f2bf(a.w);
  v[4]=f2bf(b.x); v[5]=f2bf(b.y); v[6]=f2bf(b.z); v[7]=f2bf(b.w);
  *(ushort8v*)(out + (size_t)t * (HID * INIT_DIM) + off) = v;
}

// Main: per block, gather+stage BM=64 rows (bf16, swizzled) into LDS, then
// 4 waves x 256 cols each: MFMA over K=512, bias+relu, column-sum, atomicAdd.
__global__ __launch_bounds__(256) void k_main(
    const float* __restrict__ fa, const float* __restrict__ fb, const float* __restrict__ fc,
    const int* __restrict__ na, const int* __restrict__ nb, const int* __restrict__ nc,
    const float* __restrict__ b1a, const float* __restrict__ b1b, const float* __restrict__ b1c,
    const unsigned short* __restrict__ wbf,   // [3][1024][512] bf16
    float* __restrict__ acc) {
  __shared__ __align__(16) unsigned short Asm[BM * INIT_DIM];  // 64 KB
  __shared__ int idxs[BM];

  int bx = blockIdx.x;
  int t = bx >> 10;             // 1024 blocks per type
  int mtile = bx & 1023;
  const float* feat = (t == 0) ? fa : (t == 1) ? fb : fc;
  const int*   nbr  = (t == 0) ? na : (t == 1) ? nb : nc;
  const float* bias = (t == 0) ? b1a : (t == 1) ? b1b : b1c;
  const unsigned short* W = wbf + (size_t)t * (HID * INIT_DIM);

  int tid = threadIdx.x;
  if (tid < BM) idxs[tid] = nbr[mtile * BM + tid];
  __syncthreads();

  // Stage A: 64 rows x 512 f32 -> bf16 into LDS with XOR swizzle.
  #pragma unroll
  for (int it = 0; it < 16; ++it) {
    int i = it * 256 + tid;     // chunk of 8 floats
    int r = i >> 6;
    int ck = i & 63;
    const float4* src = (const float4*)(feat + (size_t)idxs[r] * INIT_DIM + ck * 8);
    float4 a = src[0], b = src[1];
    ushort8v v;
    v[0]=f2bf(a.x); v[1]=f2bf(a.y); v[2]=f2bf(a.z); v[3]=f2bf(a.w);
    v[4]=f2bf(b.x); v[5]=f2bf(b.y); v[6]=f2bf(b.z); v[7]=f2bf(b.w);
    int byte = r * 1024 + ((ck * 16) ^ ((r & 7) << 4));
    *(ushort8v*)((char*)Asm + byte) = v;
  }
  __syncthreads();

  int wave = tid >> 6;
  int lane = tid & 63;
  int l15 = lane & 15, lg = lane >> 4;
  int nwbase = wave * 256;      // each wave owns 256 of the 1024 cols

  for (int nc_ = 0; nc_ < 4; ++nc_) {
    int nbase = nwbase + nc_ * 64;
    f32x4 accf[4][4] = {};      // [mf][nf]
    #pragma unroll 4
    for (int ks = 0; ks < 16; ++ks) {
      int k0 = ks * 32 + lg * 8;
      short8v Bf[4];
      #pragma unroll
      for (int nf = 0; nf < 4; ++nf) {
        int n = nbase + nf * 16 + l15;
        Bf[nf] = *(const short8v*)(W + (size_t)n * INIT_DIM + k0);
      }
      short8v Af[4];
      #pragma unroll
      for (int mf = 0; mf < 4; ++mf) {
        int r = mf * 16 + l15;
        int byte = r * 1024 + ((k0 * 2) ^ ((r & 7) << 4));
        Af[mf] = *(const short8v*)((const char*)Asm + byte);
      }
      #pragma unroll
      for (int mf = 0; mf < 4; ++mf)
        #pragma unroll
        for (int nf = 0; nf < 4; ++nf)
          accf[mf][nf] = __builtin_amdgcn_mfma_f32_16x16x32_bf16(Af[mf], Bf[nf], accf[mf][nf], 0, 0, 0);
    }
    // Epilogue: bias + relu + sum over the 64 rows, then one atomic per col.
    #pragma unroll
    for (int nf = 0; nf < 4; ++nf) {
      int n = nbase + nf * 16 + l15;
      float b = bias[n];
      float s = 0.f;
      #pragma unroll
      for (int mf = 0; mf < 4; ++mf)
        #pragma unroll
        for (int r = 0; r < 4; ++r) {
          float v = accf[mf][nf][r] + b;
          s += (v > 0.f) ? v : 0.f;
        }
      s += __shfl_xor(s, 16);
      s += __shfl_xor(s, 32);
      if (lg == 0) atomicAdd(acc + n, s);
    }
  }
}

// pooled = acc/196608 ; feat_all = relu ; logits = feat_all @ Wc.T + bc
__global__ __launch_bounds__(256) void k_final(const float* __restrict__ acc,
                                               const float* __restrict__ Wc,
                                               const float* __restrict__ bc,
                                               float* __restrict__ out) {
  __shared__ float fall[HID];
  int tid = threadIdx.x;
  const float inv = 1.f / (3.f * (float)N_NBR);
  for (int i = tid; i < HID; i += 256) {
    float p = acc[i] * inv;
    fall[i] = (p > 0.f) ? p : 0.f;
  }
  __syncthreads();
  int o = tid >> 2, q = tid & 3;
  const float4* w = (const float4*)(Wc + (size_t)o * HID + q * 256);
  const float4* f = (const float4*)(fall + q * 256);
  float s = 0.f;
  #pragma unroll 4
  for (int k = 0; k < 64; ++k) {
    float4 wv = w[k], fv = f[k];
    s += wv.x * fv.x + wv.y * fv.y + wv.z * fv.z + wv.w * fv.w;
  }
  s += __shfl_xor(s, 1);
  s += __shfl_xor(s, 2);
  if (q == 0) out[o] = s + bc[o];
}

extern "C" void kernel_launch(void* const* d_in, const int* in_sizes, int n_in,
                              void* d_out, int out_size, void* d_ws, size_t ws_size,
                              hipStream_t stream) {
  // inputs: 0 feat(unused), 1 fa, 2 na, 3 W1a, 4 b1a, 5 fb, 6 nb, 7 W1b, 8 b1b,
  //         9 fc, 10 nc, 11 W1c, 12 b1c, 13 Wc, 14 bc
  const float* fa  = (const float*)d_in[1];
  const int*   na  = (const int*)d_in[2];
  const float* W1a = (const float*)d_in[3];
  const float* b1a = (const float*)d_in[4];
  const float* fb  = (const float*)d_in[5];
  const int*   nb  = (const int*)d_in[6];
  const float* W1b = (const float*)d_in[7];
  const float* b1b = (const float*)d_in[8];
  const float* fc  = (const float*)d_in[9];
  const int*   nc  = (const int*)d_in[10];
  const float* W1c = (const float*)d_in[11];
  const float* b1c = (const float*)d_in[12];
  const float* Wc  = (const float*)d_in[13];
  const float* bc  = (const float*)d_in[14];
  float* out = (float*)d_out;

  float* acc = (float*)d_ws;                                   // 1024 f32
  unsigned short* wbf = (unsigned short*)((char*)d_ws + 4096); // 3 MB bf16 weights

  k_zero<<<1, 256, 0, stream>>>(acc);
  k_convw<<<768, 256, 0, stream>>>(W1a, W1b, W1c, wbf);
  k_main<<<3072, 256, 0, stream>>>(fa, fb, fc, na, nb, nc, b1a, b1b, b1c, wbf, acc);
  k_final<<<1, 256, 0, stream>>>(acc, Wc, bc, out);
}